// Round 3
// baseline (48.716 us; speedup 1.0000x reference)
//
#include <hip/hip_runtime.h>

typedef float  f32x4 __attribute__((ext_vector_type(4)));
typedef short  s16x8 __attribute__((ext_vector_type(8)));
typedef unsigned int u32;
typedef unsigned short u16;

#define B_N   8
#define C_N   128
#define HW_N  4096
#define G_N   16
#define K_N   2048
#define O_N   256
#define BN    128

typedef const __attribute__((address_space(1))) u32 gbl_u32;
typedef __attribute__((address_space(3))) u32 lds_u32;

__device__ __forceinline__ u16 bf16_bits(float f) {
  u32 u = __builtin_bit_cast(u32, f);
  u32 lsb = (u >> 16) & 1u;
  u += 0x7fffu + lsb;               // round-to-nearest-even
  return (u16)(u >> 16);
}

// ---- prep: W2 f32 [256][2048] -> bf16, laid out as the exact LDS image ----
// 32 tiles (g,kh) of 32 KB; within a tile, fragment-major:
//   byte = tile*32768 + ((mtile*2 + ks)*64 + lk*16 + lc)*16 + j*2
// for element (m = mtile*16+lc, k = g*128 + kh*64 + ks*32 + lk*8 + j).
// ds_read at (fragbase + lane*16) is then perfectly linear -> conflict-free,
// and global_load_lds (linear lane*16 dest) stages it with zero rearrangement.
__global__ void w2cvt_k(const float* __restrict__ W2, char* __restrict__ w2t) {
  int f = blockIdx.x * 256 + threadIdx.x;   // 65536 fragment-rows of 16B
  int blk = f >> 11;                        // g*2 + kh
  int r   = f & 2047;
  int mtk = r >> 6;                         // mtile*2 + ks
  int lk  = (r >> 4) & 3;
  int lc  = r & 15;
  int m   = (mtk >> 1) * 16 + lc;
  int g   = blk >> 1, kh = blk & 1, ks = mtk & 1;
  int k0  = g * 128 + kh * 64 + ks * 32 + lk * 8;
  const f32x4* src = reinterpret_cast<const f32x4*>(W2 + (size_t)m * K_N + k0);
  f32x4 v0 = src[0], v1 = src[1];
  s16x8 p;
  p[0]=bf16_bits(v0[0]); p[1]=bf16_bits(v0[1]); p[2]=bf16_bits(v0[2]); p[3]=bf16_bits(v0[3]);
  p[4]=bf16_bits(v1[0]); p[5]=bf16_bits(v1[1]); p[6]=bf16_bits(v1[2]); p[7]=bf16_bits(v1[3]);
  *reinterpret_cast<s16x8*>(w2t + (size_t)f * 16) = p;
}

// ---- main fused kernel ----
// Block: ALL 256 o x 128 px. 8 waves (4 wm x 2 wn), wave tile 64o x 64px.
// B-fragments (x) live in regs for the whole K loop; A double-buffered in LDS.
__launch_bounds__(512, 2)
__global__ void ccattn_main_k(const float* __restrict__ x,
                              const float* __restrict__ W1,
                              const float* __restrict__ b1,
                              const char* __restrict__ w2t,
                              const float* __restrict__ b2,
                              float* __restrict__ out) {
  __shared__ __align__(16) char Abuf[2][32768];   // 64 KB, A half-group dbuf
  __shared__ u16   xT[BN * C_N];                  // 32 KB
  __shared__ float fmT[G_N][BN];                  // 8 KB

  const int tid = threadIdx.x;
  const int bid = blockIdx.x;
  const int b   = bid >> 5;
  const int px0 = (bid & 31) * BN;

  const int w  = tid >> 6;
  const int l  = tid & 63;

  // ---- stage A tile 0 first (latency overlaps x staging) ----
  auto stage = [&](int tile, int bufsel) {
    const char* src = w2t + (size_t)tile * 32768 + w * 1024 + l * 16;
    char* dst = &Abuf[bufsel][w * 1024];
#pragma unroll
    for (int r = 0; r < 4; ++r)
      __builtin_amdgcn_global_load_lds((gbl_u32*)(src + r * 8192),
                                       (lds_u32*)(dst + r * 8192), 16, 0, 0);
  };
  stage(0, 0);

  // ---- staging: xT (bf16 [px][c], swizzled) + fm ----
  {
    const float* xb = x + (size_t)b * C_N * HW_N + px0;
    const int px = tid & 127;
    const int cq = tid >> 7;             // 4 groups each
#pragma unroll
    for (int gg = 0; gg < 4; ++gg) {
      const int g  = cq * 4 + gg;
      const int c0 = g * 8;
      float v[8];
#pragma unroll
      for (int j = 0; j < 8; ++j) v[j] = xb[(size_t)(c0 + j) * HW_N + px];
      float s = b1[g];
#pragma unroll
      for (int j = 0; j < 8; ++j) s += v[j] * W1[g * 8 + j];
      fmT[g][px] = fmaxf(s, 0.0f);
      s16x8 p;
#pragma unroll
      for (int j = 0; j < 8; ++j) p[j] = (short)bf16_bits(v[j]);
      int byte = (px * 256 + c0 * 2) ^ ((px & 15) << 4);
      *reinterpret_cast<s16x8*>(reinterpret_cast<char*>(xT) + byte) = p;
    }
  }
  __syncthreads();   // xT/fm ready AND (vmcnt drain) A tile 0 ready

  // ---- wave decomposition ----
  const int wm = w & 3;                  // o quarter
  const int wn = w >> 2;                 // px half
  const int lc = l & 15;
  const int lk = l >> 4;

  // ---- B-fragment register cache [ks4][nf] (all 128 channels of a group) ----
  s16x8 bfr[4][4];
#pragma unroll
  for (int ks = 0; ks < 4; ++ks)
#pragma unroll
    for (int nf = 0; nf < 4; ++nf) {
      int px  = wn * 64 + nf * 16 + lc;
      int byte = (px * 256 + (ks * 32 + lk * 8) * 2) ^ ((px & 15) << 4);
      bfr[ks][nf] = *reinterpret_cast<const s16x8*>(
          reinterpret_cast<const char*>(xT) + byte);
    }

  f32x4 acc[4][4];
  const f32x4 Z = {0.f, 0.f, 0.f, 0.f};
#pragma unroll
  for (int mf = 0; mf < 4; ++mf)
#pragma unroll
    for (int nf = 0; nf < 4; ++nf) acc[mf][nf] = Z;

  // per-mf fragment base within a half-group tile
  const int fbase = l * 16;

  // ---- main loop: 16 groups x 2 half-tiles, 2-phase pipelined ----
#pragma unroll 1
  for (int g = 0; g < 16; ++g) {
    f32x4 P[4][4];
    // half-tile A (even): buffer 0, channels [0,64)
    stage(2 * g + 1, 1);
    {
      const char* ab = Abuf[0];
      s16x8 afr[2][4];
#pragma unroll
      for (int ks = 0; ks < 2; ++ks)
#pragma unroll
        for (int mf = 0; mf < 4; ++mf)
          afr[ks][mf] = *reinterpret_cast<const s16x8*>(
              ab + ((wm * 4 + mf) * 2 + ks) * 1024 + fbase);
#pragma unroll
      for (int mf = 0; mf < 4; ++mf)
#pragma unroll
        for (int nf = 0; nf < 4; ++nf)
          P[mf][nf] = __builtin_amdgcn_mfma_f32_16x16x32_bf16(
              afr[0][mf], bfr[0][nf], Z, 0, 0, 0);
#pragma unroll
      for (int mf = 0; mf < 4; ++mf)
#pragma unroll
        for (int nf = 0; nf < 4; ++nf)
          P[mf][nf] = __builtin_amdgcn_mfma_f32_16x16x32_bf16(
              afr[1][mf], bfr[1][nf], P[mf][nf], 0, 0, 0);
    }
    __syncthreads();   // drains stage(2g+1); all waves done with Abuf[0]

    // half-tile B (odd): buffer 1, channels [64,128)
    if (g < 15) stage(2 * g + 2, 0);
    float sn[4];
#pragma unroll
    for (int nf = 0; nf < 4; ++nf) sn[nf] = fmT[g][wn * 64 + nf * 16 + lc];
    {
      const char* ab = Abuf[1];
      s16x8 afr[2][4];
#pragma unroll
      for (int ks = 0; ks < 2; ++ks)
#pragma unroll
        for (int mf = 0; mf < 4; ++mf)
          afr[ks][mf] = *reinterpret_cast<const s16x8*>(
              ab + ((wm * 4 + mf) * 2 + ks) * 1024 + fbase);
#pragma unroll
      for (int mf = 0; mf < 4; ++mf)
#pragma unroll
        for (int nf = 0; nf < 4; ++nf)
          P[mf][nf] = __builtin_amdgcn_mfma_f32_16x16x32_bf16(
              afr[0][mf], bfr[2][nf], P[mf][nf], 0, 0, 0);
#pragma unroll
      for (int mf = 0; mf < 4; ++mf)
#pragma unroll
        for (int nf = 0; nf < 4; ++nf)
          P[mf][nf] = __builtin_amdgcn_mfma_f32_16x16x32_bf16(
              afr[1][mf], bfr[3][nf], P[mf][nf], 0, 0, 0);
    }
    // fold group into acc: acc += fm[g,px] * P
#pragma unroll
    for (int mf = 0; mf < 4; ++mf)
#pragma unroll
      for (int nf = 0; nf < 4; ++nf)
#pragma unroll
        for (int i = 0; i < 4; ++i)
          acc[mf][nf][i] += sn[nf] * P[mf][nf][i];
    __syncthreads();   // drains stage(2g+2); all waves done with Abuf[1]
  }

  // ---- epilogue: bias + store ----
  float* outb = out + (size_t)b * O_N * HW_N + px0;
#pragma unroll
  for (int mf = 0; mf < 4; ++mf) {
    int o0 = wm * 64 + mf * 16 + lk * 4;
#pragma unroll
    for (int i = 0; i < 4; ++i) {
      float bias = b2[o0 + i];
#pragma unroll
      for (int nf = 0; nf < 4; ++nf) {
        int px = wn * 64 + nf * 16 + lc;
        outb[(size_t)(o0 + i) * HW_N + px] = acc[mf][nf][i] + bias;
      }
    }
  }
}

extern "C" void kernel_launch(void* const* d_in, const int* in_sizes, int n_in,
                              void* d_out, int out_size, void* d_ws, size_t ws_size,
                              hipStream_t stream) {
  const float* x  = (const float*)d_in[0];
  const float* W1 = (const float*)d_in[1];
  const float* b1 = (const float*)d_in[2];
  const float* W2 = (const float*)d_in[3];
  const float* b2 = (const float*)d_in[4];
  float* out = (float*)d_out;
  char* w2t = (char*)d_ws;             // 1 MB tiled bf16 copy of W2

  w2cvt_k<<<256, 256, 0, stream>>>(W2, w2t);
  ccattn_main_k<<<256, 512, 0, stream>>>(x, W1, b1, w2t, b2, out);
}